// Round 1
// baseline (570.750 us; speedup 1.0000x reference)
//
#include <hip/hip_runtime.h>

#define EPS 1e-5f
#define APITCH 264   // bf16 tile row pitch (shorts): 256 + 8 pad, 16B-aligned rows
#define FPITCH 516   // f32 tile row pitch (floats): 512 + 4 pad
#define IOPITCH 260  // f32 256-wide buffer pitch

typedef __attribute__((ext_vector_type(8))) short bf16x8;
typedef __attribute__((ext_vector_type(4))) float f32x4;

__device__ __forceinline__ unsigned short f2b(float f) {
  unsigned int u = __builtin_bit_cast(unsigned int, f);
  u += 0x7fffu + ((u >> 16) & 1u);   // round-to-nearest-even
  return (unsigned short)(u >> 16);
}

// out32xOUT = aT(32x256 bf16, LDS) @ Wb^T (OUT x 256 bf16, global) + bias -> fBuf (f32, LDS)
// 4 waves; each wave owns `nct` 16-wide column tiles. ct-pairs processed with
// b-fragments hoisted to registers (reused across both 16-row tiles).
__device__ __forceinline__ void gemm32(const short* aT,
                                       const unsigned short* __restrict__ Wb,
                                       const float* __restrict__ bias,
                                       float* fBuf, int fcolBase, int nct,
                                       int wv, int lane) {
  const int lr = lane & 15, lh = lane >> 4;
  for (int cp = 0; cp < nct; cp += 2) {
    const int ct0 = wv * nct + cp, ct1 = ct0 + 1;
    bf16x8 b0[8], b1[8];
#pragma unroll
    for (int kk = 0; kk < 8; kk++) {
      b0[kk] = *(const bf16x8*)&Wb[(ct0 * 16 + lr) * 256 + kk * 32 + lh * 8];
      b1[kk] = *(const bf16x8*)&Wb[(ct1 * 16 + lr) * 256 + kk * 32 + lh * 8];
    }
    const float bias0 = bias[ct0 * 16 + lr], bias1 = bias[ct1 * 16 + lr];
    f32x4 a00 = {0.f, 0.f, 0.f, 0.f}, a01 = a00, a10 = a00, a11 = a00;
#pragma unroll
    for (int kk = 0; kk < 8; kk++) {
      bf16x8 x0 = *(const bf16x8*)&aT[lr * APITCH + kk * 32 + lh * 8];
      bf16x8 x1 = *(const bf16x8*)&aT[(16 + lr) * APITCH + kk * 32 + lh * 8];
      a00 = __builtin_amdgcn_mfma_f32_16x16x32_bf16(x0, b0[kk], a00, 0, 0, 0);
      a10 = __builtin_amdgcn_mfma_f32_16x16x32_bf16(x1, b0[kk], a10, 0, 0, 0);
      a01 = __builtin_amdgcn_mfma_f32_16x16x32_bf16(x0, b1[kk], a01, 0, 0, 0);
      a11 = __builtin_amdgcn_mfma_f32_16x16x32_bf16(x1, b1[kk], a11, 0, 0, 0);
    }
#pragma unroll
    for (int i = 0; i < 4; i++) {
      const int rw = lh * 4 + i;
      fBuf[rw * FPITCH + fcolBase + ct0 * 16 + lr] = a00[i] + bias0;
      fBuf[rw * FPITCH + fcolBase + ct1 * 16 + lr] = a01[i] + bias1;
      fBuf[(16 + rw) * FPITCH + fcolBase + ct0 * 16 + lr] = a10[i] + bias0;
      fBuf[(16 + rw) * FPITCH + fcolBase + ct1 * 16 + lr] = a11[i] + bias1;
    }
  }
}

// 32 rows x 256 f32 (global, coalesced float4) -> bf16 LDS tile
__device__ __forceinline__ void load_rows_bf16(const float* __restrict__ src,
                                               short* aT, int t) {
#pragma unroll
  for (int j = 0; j < 8; j++) {
    const int idx4 = j * 256 + t;
    const int row = idx4 >> 6;
    const int c4 = (idx4 & 63) << 2;
    const float4 v = *(const float4*)&src[row * 256 + c4];
    short* p = &aT[row * APITCH + c4];
    p[0] = (short)f2b(v.x); p[1] = (short)f2b(v.y);
    p[2] = (short)f2b(v.z); p[3] = (short)f2b(v.w);
  }
}

__device__ __forceinline__ void red8(float& s, float& q) {
#pragma unroll
  for (int m = 1; m < 8; m <<= 1) { s += __shfl_xor(s, m); q += __shfl_xor(q, m); }
}

// kernel 1: params = uf @ dyn_W^T + dyn_b ; param_in (f32) and LN(param_out) -> ws
__global__ __launch_bounds__(256) void k_params(
    const float* __restrict__ uf, const unsigned short* __restrict__ dynW,
    const float* __restrict__ dynb, const float* __restrict__ nog,
    const float* __restrict__ nob, float* __restrict__ param_in,
    float* __restrict__ param_out_ln) {
  __shared__ short aT[32 * APITCH];
  __shared__ float fBuf[32 * FPITCH];
  const int t = threadIdx.x;
  const int r0 = blockIdx.x * 32;
  load_rows_bf16(&uf[(size_t)r0 * 256], aT, t);
  __syncthreads();
  gemm32(aT, dynW, dynb, fBuf, 0, 8, t >> 6, t & 63);
  __syncthreads();
  const int row = t >> 3, j = t & 7;
  float s = 0.f, q = 0.f;
#pragma unroll
  for (int i = 0; i < 32; i++) {
    float x = fBuf[row * FPITCH + 256 + j + 8 * i];
    s += x; q += x * x;
  }
  red8(s, q);
  const float mu = s * (1.f / 256.f);
  const float rs = rsqrtf(q * (1.f / 256.f) - mu * mu + EPS);
  for (int i = 0; i < 32; i++) {
    const int c = j + 8 * i;
    float x = fBuf[row * FPITCH + 256 + c];
    param_out_ln[(size_t)(r0 + row) * 256 + c] = (x - mu) * rs * nog[c] + nob[c];
  }
#pragma unroll
  for (int jj = 0; jj < 8; jj++) {
    const int idx4 = jj * 256 + t;
    const int rw = idx4 >> 6;
    const int c4 = (idx4 & 63) << 2;
    float4 v;
    v.x = fBuf[rw * FPITCH + c4 + 0];
    v.y = fBuf[rw * FPITCH + c4 + 1];
    v.z = fBuf[rw * FPITCH + c4 + 2];
    v.w = fBuf[rw * FPITCH + c4 + 3];
    *(float4*)&param_in[(size_t)(r0 + rw) * 256 + c4] = v;
  }
}

// kernel 2: fully fused per 32-row tile of (n,k) rows
__global__ __launch_bounds__(256) void k_main(
    const float* __restrict__ inf, const unsigned short* __restrict__ inpW,
    const float* __restrict__ inpb, const unsigned short* __restrict__ igW,
    const float* __restrict__ igb, const unsigned short* __restrict__ ugW,
    const float* __restrict__ ugb, const unsigned short* __restrict__ fcW,
    const float* __restrict__ fcb,
    const float* __restrict__ nig, const float* __restrict__ nib,   // norm_in (update gate)
    const float* __restrict__ iig, const float* __restrict__ iib,   // inorm_in (input gate)
    const float* __restrict__ iog, const float* __restrict__ iob,   // inorm_out
    const float* __restrict__ fng, const float* __restrict__ fnb,   // fc_norm
    const float* __restrict__ param_in, const float* __restrict__ param_out_ln,
    float* __restrict__ out) {
  __shared__ short aT[32 * APITCH];
  __shared__ float fBuf[32 * FPITCH];
  __shared__ float ioLN[32 * IOPITCH];
  __shared__ float muA[32], rsA[32];
  const int t = threadIdx.x;
  const int r0 = blockIdx.x * 32;
  load_rows_bf16(&inf[(size_t)r0 * 256], aT, t);
  __syncthreads();
  const int wv = t >> 6, lane = t & 63;
  // GEMM1: input_feats (32 x 512)
  gemm32(aT, inpW, inpb, fBuf, 0, 8, wv, lane);
  __syncthreads();
  const int row = t >> 3, j = t & 7;
  const int n = (r0 + row) / 9;
  {
    // LN(input_out) -> ioLN ; gate_feats = input_in * param_in[n] -> aT (bf16)
    float s = 0.f, q = 0.f;
#pragma unroll
    for (int i = 0; i < 32; i++) {
      float x = fBuf[row * FPITCH + 256 + j + 8 * i];
      s += x; q += x * x;
    }
    red8(s, q);
    const float mu = s * (1.f / 256.f);
    const float rs = rsqrtf(q * (1.f / 256.f) - mu * mu + EPS);
    for (int i = 0; i < 32; i++) {
      const int c = j + 8 * i;
      float io = fBuf[row * FPITCH + 256 + c];
      ioLN[row * IOPITCH + c] = (io - mu) * rs * iog[c] + iob[c];
      float gf = fBuf[row * FPITCH + c] * param_in[(size_t)n * 256 + c];
      aT[row * APITCH + c] = (short)f2b(gf);
    }
  }
  __syncthreads();
  // GEMM2/3: P = gate@ig^T -> cols 0..255 ; U = gate@ug^T -> cols 256..511
  gemm32(aT, igW, igb, fBuf, 0, 4, wv, lane);
  gemm32(aT, ugW, ugb, fBuf, 256, 4, wv, lane);
  __syncthreads();
  {
    float sp = 0.f, qp = 0.f, su = 0.f, qu = 0.f;
#pragma unroll
    for (int i = 0; i < 32; i++) {
      float p = fBuf[row * FPITCH + j + 8 * i];       sp += p; qp += p * p;
      float u = fBuf[row * FPITCH + 256 + j + 8 * i]; su += u; qu += u * u;
    }
    red8(sp, qp); red8(su, qu);
    const float muP = sp * (1.f / 256.f);
    const float rsP = rsqrtf(qp * (1.f / 256.f) - muP * muP + EPS);
    const float muU = su * (1.f / 256.f);
    const float rsU = rsqrtf(qu * (1.f / 256.f) - muU * muU + EPS);
    for (int i = 0; i < 32; i++) {
      const int c = j + 8 * i;
      float p = (fBuf[row * FPITCH + c] - muP) * rsP * iig[c] + iib[c];
      float g1 = 1.f / (1.f + __expf(-p));
      float u = (fBuf[row * FPITCH + 256 + c] - muU) * rsU * nig[c] + nib[c];
      float g2 = 1.f / (1.f + __expf(-u));
      float ft = g2 * param_out_ln[(size_t)n * 256 + c] + g1 * ioLN[row * IOPITCH + c];
      aT[row * APITCH + c] = (short)f2b(ft);
    }
  }
  __syncthreads();
  // GEMM4: features @ fc^T -> cols 0..255
  gemm32(aT, fcW, fcb, fBuf, 0, 4, wv, lane);
  __syncthreads();
  {
    float s = 0.f, q = 0.f;
#pragma unroll
    for (int i = 0; i < 32; i++) {
      float x = fBuf[row * FPITCH + j + 8 * i];
      s += x; q += x * x;
    }
    red8(s, q);
    const float mu = s * (1.f / 256.f);
    const float rs = rsqrtf(q * (1.f / 256.f) - mu * mu + EPS);
    if (j == 0) { muA[row] = mu; rsA[row] = rs; }
  }
  __syncthreads();
#pragma unroll
  for (int jj = 0; jj < 8; jj++) {
    const int idx4 = jj * 256 + t;
    const int rw = idx4 >> 6;
    const int c4 = (idx4 & 63) << 2;
    const float mu = muA[rw], rs = rsA[rw];
    const float4 g4 = *(const float4*)&fng[c4];
    const float4 b4 = *(const float4*)&fnb[c4];
    float4 v;
    v.x = fmaxf((fBuf[rw * FPITCH + c4 + 0] - mu) * rs * g4.x + b4.x, 0.f);
    v.y = fmaxf((fBuf[rw * FPITCH + c4 + 1] - mu) * rs * g4.y + b4.y, 0.f);
    v.z = fmaxf((fBuf[rw * FPITCH + c4 + 2] - mu) * rs * g4.z + b4.z, 0.f);
    v.w = fmaxf((fBuf[rw * FPITCH + c4 + 3] - mu) * rs * g4.w + b4.w, 0.f);
    *(float4*)&out[(size_t)(r0 + rw) * 256 + c4] = v;
  }
}

__global__ void k_cvt(const float* __restrict__ src,
                      unsigned short* __restrict__ dst, int n) {
  int i = blockIdx.x * blockDim.x + threadIdx.x;
  if (i < n) dst[i] = f2b(src[i]);
}

extern "C" void kernel_launch(void* const* d_in, const int* in_sizes, int n_in,
                              void* d_out, int out_size, void* d_ws, size_t ws_size,
                              hipStream_t stream) {
  const float* uf   = (const float*)d_in[0];
  const float* inf  = (const float*)d_in[1];
  const float* dynW = (const float*)d_in[2];
  const float* dynb = (const float*)d_in[3];
  const float* inpW = (const float*)d_in[4];
  const float* inpb = (const float*)d_in[5];
  const float* igW  = (const float*)d_in[6];
  const float* igb  = (const float*)d_in[7];
  const float* ugW  = (const float*)d_in[8];
  const float* ugb  = (const float*)d_in[9];
  const float* fcW  = (const float*)d_in[10];
  const float* fcb  = (const float*)d_in[11];
  const float* nig  = (const float*)d_in[12];
  const float* nib  = (const float*)d_in[13];
  const float* nog  = (const float*)d_in[14];
  const float* nob  = (const float*)d_in[15];
  const float* iig  = (const float*)d_in[16];
  const float* iib  = (const float*)d_in[17];
  const float* iog  = (const float*)d_in[18];
  const float* iob  = (const float*)d_in[19];
  const float* fng  = (const float*)d_in[20];
  const float* fnb  = (const float*)d_in[21];
  float* out = (float*)d_out;

  char* ws = (char*)d_ws;
  unsigned short* dynWb = (unsigned short*)(ws + 0);        // 512*256*2 = 262144
  unsigned short* inpWb = (unsigned short*)(ws + 262144);   // 262144
  unsigned short* igWb  = (unsigned short*)(ws + 524288);   // 131072
  unsigned short* ugWb  = (unsigned short*)(ws + 655360);   // 131072
  unsigned short* fcWb  = (unsigned short*)(ws + 786432);   // 131072
  float* param_in     = (float*)(ws + (1 << 20));                 // 16 MB
  float* param_out_ln = (float*)(ws + (1 << 20) + (16 << 20));    // 16 MB

  k_cvt<<<dim3(512), dim3(256), 0, stream>>>(dynW, dynWb, 131072);
  k_cvt<<<dim3(512), dim3(256), 0, stream>>>(inpW, inpWb, 131072);
  k_cvt<<<dim3(256), dim3(256), 0, stream>>>(igW, igWb, 65536);
  k_cvt<<<dim3(256), dim3(256), 0, stream>>>(ugW, ugWb, 65536);
  k_cvt<<<dim3(256), dim3(256), 0, stream>>>(fcW, fcWb, 65536);

  k_params<<<dim3(512), dim3(256), 0, stream>>>(uf, dynWb, dynb, nog, nob,
                                                param_in, param_out_ln);

  k_main<<<dim3(4608), dim3(256), 0, stream>>>(
      inf, inpWb, inpb, igWb, igb, ugWb, ugb, fcWb, fcb,
      nig, nib, iig, iib, iog, iob, fng, fnb,
      param_in, param_out_ln, out);
}